// Round 12
// baseline (211116.138 us; speedup 1.0000x reference)
//
#include <hip/hip_runtime.h>

namespace {

constexpr int NB  = 64;
constexpr int NN  = 50;
constexpr int DM  = 128;
constexpr int NHD = 8;
constexpr int HDM = 16;
constexpr int KA  = 15;
constexpr int KS  = 35;
constexpr int TA  = 16;
constexpr int TS  = 37;
constexpr int NT  = 512;    // 8 waves: wave w owns cols [w*16, w*16+16) of each 128-col block
constexpr int LDH = 132;    // padded stride for T x 128 activation tiles (bank-spread)
constexpr int LDF = 260;    // padded stride for T x 256 tiles
constexpr float BIGF = 1000000000.0f;

// dynamic LDS layout (floats)
constexpr int OFF_HA   = 0;                    // 16*132  = 2112
constexpr int OFF_HS   = OFF_HA + TA * LDH;    // 2112
constexpr int OFF_BIAS = OFF_HS + TS * LDH;    // 6996
constexpr int B_ATTN_A = 0, B_ATTN_S = 1024, B_FF1_A = 2048, B_FF1_S = 3072;
constexpr int B_FF2_A  = 4096, B_FF2_S = 4352, B_K = 4608, B_V = 4864;
constexpr int BIAS_FLOATS = 5120;
constexpr int OFF_WBUF = OFF_BIAS + BIAS_FLOATS;   // 12116 ; 8 waves x 1024 fl (4 chunk bufs)
constexpr int OFF_SCR  = OFF_WBUF + 8192;          // 20308 ; scores also live in WBUF region
constexpr int SCR_FLOATS = 3 * TS * LDH;           // 14652
constexpr int SMEM_FLOATS = OFF_SCR + SCR_FLOATS;  // 34960
constexpr int SMEM_BYTES  = SMEM_FLOATS * 4;       // 139840 B

struct Params {
  const float* x; const int* start;
  const float* a_emb_W; const float* a_emb_b;
  const float* a_attn_W; const float* a_attn_b;
  const float* a_ff_W1; const float* a_ff_b1;
  const float* a_ff_W2; const float* a_ff_b2;
  const float* a_ln;
  const float* s_emb_W; const float* s_emb_b;
  const float* s_attn_W; const float* s_attn_b;
  const float* s_ff_W1; const float* s_ff_b1;
  const float* s_ff_W2; const float* s_ff_b2;
  const float* s_ln;
  const float* WK; const float* bK;
  const float* WV; const float* bV;
  const float* Wq_mlp; const float* bq_mlp;
  const float* d_Wq; const float* d_bq;
  const float* d_Wo; const float* d_bo;
  float* out;   // f32: tours (64x50) ++ logp (64)
};

#define GLD16(gp, lp) \
  __builtin_amdgcn_global_load_lds((const __attribute__((address_space(1))) void*)(gp), \
                                   (__attribute__((address_space(3))) void*)(lp), 16, 0, 0)
// Full drain: immune to vmcnt miscounting from any flat/global ops in the region.
#define WAITV0() asm volatile("s_waitcnt vmcnt(0)" ::: "memory")

#define FMA16_(aa, i, w0, w1, w2, w3) \
  acc[i].x = fmaf((aa).x,(w0).x,acc[i].x); acc[i].y = fmaf((aa).x,(w0).y,acc[i].y); \
  acc[i].z = fmaf((aa).x,(w0).z,acc[i].z); acc[i].w = fmaf((aa).x,(w0).w,acc[i].w); \
  acc[i].x = fmaf((aa).y,(w1).x,acc[i].x); acc[i].y = fmaf((aa).y,(w1).y,acc[i].y); \
  acc[i].z = fmaf((aa).y,(w1).z,acc[i].z); acc[i].w = fmaf((aa).y,(w1).w,acc[i].w); \
  acc[i].x = fmaf((aa).z,(w2).x,acc[i].x); acc[i].y = fmaf((aa).z,(w2).y,acc[i].y); \
  acc[i].z = fmaf((aa).z,(w2).z,acc[i].z); acc[i].w = fmaf((aa).z,(w2).w,acc[i].w); \
  acc[i].x = fmaf((aa).w,(w3).x,acc[i].x); acc[i].y = fmaf((aa).w,(w3).y,acc[i].y); \
  acc[i].z = fmaf((aa).w,(w3).z,acc[i].z); acc[i].w = fmaf((aa).w,(w3).w,acc[i].w);

// Barrier-free wave-group matmul: out[T x NBLK*128] = in[T x NCH*16] @ W + biasLDS (+relu).
// Wave w owns cols [w*16, w*16+16) of every 128-col block -> weight staging is wave-private
// (global_load_lds chunks of 16k x 16cols = 1KB). Groups of 2 chunks, double-buffered:
//   wait vmcnt(0)  [current group landed; over-waits strays -> always correct]
//   issue next group (2 gld_lds)
//   compute current group (~1.5K cy hides the next group's latency)
// No __syncthreads inside; caller barriers before/after. Zero weight redundancy.
template<int NCH, int R, int NBLK>
__device__ __forceinline__ void matmul_grp(const float* __restrict__ in, int lda,
                                           const float* __restrict__ W, int ldw, int wBlk,
                                           const float* __restrict__ biasL,  // LDS, 128/block
                                           float* __restrict__ out, int ldo, int oBlk,
                                           float* __restrict__ wvb,          // wave's 1024 fl
                                           int T, bool relu, bool accum, int tid)
{
  static_assert(NCH % 2 == 0, "NCH even");
  constexpr int NG = NCH / 2;
  const int lane = tid & 63;
  const int c4   = lane & 3;
  const int g    = lane >> 2;
  const int colb = (tid >> 6) << 4;    // wave's col base within a 128-col block
  int rows[R];
#pragma unroll
  for (int i = 0; i < R; ++i) rows[i] = min(g * R + i, T - 1);
  for (int blk = 0; blk < NBLK; ++blk) {
    const float* __restrict__ wsrc = W + (size_t)blk * wBlk + (size_t)g * ldw + colb + c4 * 4;
    float4 acc[R];
    if (accum) {
#pragma unroll
      for (int i = 0; i < R; ++i)
        acc[i] = *(const float4*)(out + (size_t)blk * oBlk + rows[i] * ldo + colb + c4 * 4);
    } else {
#pragma unroll
      for (int i = 0; i < R; ++i) acc[i] = make_float4(0.f, 0.f, 0.f, 0.f);
    }
    // prologue: group 0 (chunks 0,1) in flight
    GLD16(wsrc + (size_t)0 * 16 * ldw, wvb + 0 * 256);
    GLD16(wsrc + (size_t)1 * 16 * ldw, wvb + 1 * 256);
#pragma unroll
    for (int gi = 0; gi < NG; ++gi) {
      WAITV0();                               // current group landed (drains strays too)
      __builtin_amdgcn_sched_barrier(0);
      if (gi + 1 < NG) {                      // issue next group into the other buffer pair
        GLD16(wsrc + (size_t)(2 * gi + 2) * 16 * ldw, wvb + (((gi + 1) & 1) * 2 + 0) * 256);
        GLD16(wsrc + (size_t)(2 * gi + 3) * 16 * ldw, wvb + (((gi + 1) & 1) * 2 + 1) * 256);
      }
#pragma unroll
      for (int cc = 0; cc < 2; ++cc) {
        const int c = 2 * gi + cc;
        const float* __restrict__ wb = wvb + ((gi & 1) * 2 + cc) * 256;
        const float* __restrict__ ip = in + c * 16;
#pragma unroll
        for (int k4 = 0; k4 < 4; ++k4) {
          float4 w0 = *(const float4*)(wb + (k4 * 16 +  0 + c4) * 4);
          float4 w1 = *(const float4*)(wb + (k4 * 16 +  4 + c4) * 4);
          float4 w2 = *(const float4*)(wb + (k4 * 16 +  8 + c4) * 4);
          float4 w3 = *(const float4*)(wb + (k4 * 16 + 12 + c4) * 4);
#pragma unroll
          for (int i = 0; i < R; ++i) {
            float4 a = *(const float4*)(ip + rows[i] * lda + k4 * 4);
            FMA16_(a, i, w0, w1, w2, w3);
          }
        }
      }
    }
    if (!accum) {
      const float4 bv = *(const float4*)(biasL + blk * 128 + colb + c4 * 4);
#pragma unroll
      for (int i = 0; i < R; ++i) {
        acc[i].x += bv.x; acc[i].y += bv.y; acc[i].z += bv.z; acc[i].w += bv.w;
      }
    }
#pragma unroll
    for (int i = 0; i < R; ++i) {
      if (g * R + i < T) {
        float4 r2 = acc[i];
        if (relu) {
          r2.x = fmaxf(r2.x, 0.f); r2.y = fmaxf(r2.y, 0.f);
          r2.z = fmaxf(r2.z, 0.f); r2.w = fmaxf(r2.w, 0.f);
        }
        *(float4*)(out + (size_t)blk * oBlk + (g * R + i) * ldo + colb + c4 * 4) = r2;
      }
    }
  }
}

// out[0..128) = bias + in(1xK) @ W(Kx128). K sliced 4-way, LDS-reduced. 2 barriers.
__device__ __forceinline__ void matvec128(const float* __restrict__ in, const float* __restrict__ W,
                                          const float* __restrict__ bias, float* __restrict__ out,
                                          int K, float* __restrict__ red, int tid)
{
  const int c = tid & 127;
  const int s = tid >> 7;
  const int ks = K >> 2;
  const int k0 = s * ks;
  float acc = 0.f;
#pragma unroll 16
  for (int k = k0; k < k0 + ks; ++k) acc = fmaf(in[k], W[(size_t)k * 128 + c], acc);
  red[tid] = acc;
  __syncthreads();
  if (tid < 128) out[c] = bias[c] + ((red[c] + red[128 + c]) + (red[256 + c] + red[384 + c]));
  __syncthreads();
}

// h[r] = LN(h[r] + a1[r]). One wave per row. Strides LDH.
__device__ __forceinline__ void layernorm_add(float* __restrict__ h, const float* __restrict__ a1,
                                              const float* __restrict__ g, const float* __restrict__ bta,
                                              int T, int tid)
{
  const int lane = tid & 63;
  const int wvl = tid >> 6;
  for (int r = wvl; r < T; r += NT / 64) {
    float v0 = h[r * LDH + lane]      + a1[r * LDH + lane];
    float v1 = h[r * LDH + lane + 64] + a1[r * LDH + lane + 64];
    float sum = v0 + v1;
    for (int off = 32; off; off >>= 1) sum += __shfl_xor(sum, off);
    float mu = sum * (1.0f / 128.0f);
    float d0 = v0 - mu, d1 = v1 - mu;
    float sq = d0 * d0 + d1 * d1;
    for (int off = 32; off; off >>= 1) sq += __shfl_xor(sq, off);
    float rs = 1.0f / sqrtf(sq * (1.0f / 128.0f) + 1e-5f);
    h[r * LDH + lane]      = g[lane]      * d0 * rs + bta[lane];
    h[r * LDH + lane + 64] = g[lane + 64] * d1 * rs + bta[lane + 64];
  }
}

// 2-layer post-LN transformer encoder. h: T x 128 (stride LDH), persists.
// scr: q,k,v at T*LDH spacing; hidden (T x 256, stride LDF) overlays q,k; ff2 accums into v.
// swb: scores (4 heads/chunk) in the WBUF region (rings idle during attn math).
template<int T, int R>
__device__ void encode_block(float* __restrict__ h, float* __restrict__ scr,
                             float* __restrict__ swb, float* __restrict__ wvb,
                             const float* __restrict__ tok,
                             const float* __restrict__ embW, const float* __restrict__ embB,
                             const float* __restrict__ attnW, const float* __restrict__ biasAttnL,
                             const float* __restrict__ W1, const float* __restrict__ biasB1L,
                             const float* __restrict__ W2, const float* __restrict__ biasB2L,
                             const float* __restrict__ ln, int tid)
{
  const int lane = tid & 63;
  const int wvl = tid >> 6;
  constexpr int TT = T * T;
  float* q = scr;
  float* k = scr + T * LDH;
  float* v = scr + 2 * T * LDH;
  float* hidden = scr;           // T x 256 (stride LDF) over q,k (dead in FF phase)
  // embedding
  for (int idx = tid; idx < T * DM; idx += NT) {
    int r = idx >> 7, c = idx & 127;
    h[r * LDH + c] = tok[2 * r] * embW[c] + tok[2 * r + 1] * embW[DM + c] + embB[c];
  }
  __syncthreads();
  for (int l = 0; l < 2; ++l) {
    const float* Wl = attnW + (size_t)(l * 4) * DM * DM;
    // fused QKV: 3 blocks of 128 cols
    matmul_grp<8, R, 3>(h, LDH, Wl, DM, DM * DM, biasAttnL + l * 512,
                        q, LDH, T * LDH, wvb, T, false, false, tid);
    __syncthreads();
    for (int hc = 0; hc < 2; ++hc) {
      // scores for heads hc*4..hc*4+3
      for (int idx = tid; idx < 4 * TT; idx += NT) {
        int hd4 = idx / TT; int rem = idx - hd4 * TT; int i = rem / T; int j = rem - i * T;
        int hd = hc * 4 + hd4;
        const float4* q4 = (const float4*)(q + i * LDH + hd * HDM);
        const float4* k4 = (const float4*)(k + j * LDH + hd * HDM);
        float acc = 0.f;
#pragma unroll
        for (int d = 0; d < 4; ++d) {
          float4 qa = q4[d], ka = k4[d];
          acc += qa.x * ka.x + qa.y * ka.y + qa.z * ka.z + qa.w * ka.w;
        }
        swb[idx] = acc * 0.25f;
      }
      __syncthreads();
      // row softmax over 4*T rows
      for (int r = wvl; r < 4 * T; r += NT / 64) {
        float val = (lane < T) ? swb[r * T + lane] : -INFINITY;
        float mx = val;
        for (int off = 32; off; off >>= 1) mx = fmaxf(mx, __shfl_xor(mx, off));
        float e = (lane < T) ? expf(val - mx) : 0.f;
        float sum = e;
        for (int off = 32; off; off >>= 1) sum += __shfl_xor(sum, off);
        if (lane < T) swb[r * T + lane] = e / sum;
      }
      __syncthreads();
      // AV for this chunk's 64 cols -> q (those q cols are dead now)
      for (int idx = tid; idx < T * 64; idx += NT) {
        int i = idx >> 6; int cc = idx & 63; int col = hc * 64 + cc; int hd4 = cc >> 4;
        const float* ar = swb + (hd4 * T + i) * T;
        float acc = 0.f;
#pragma unroll 4
        for (int j = 0; j < T; ++j) acc = fmaf(ar[j], v[j * LDH + col], acc);
        q[i * LDH + col] = acc;
      }
      __syncthreads();
    }
    // Wo: q -> v (v dead)
    matmul_grp<8, R, 1>(q, LDH, Wl + (size_t)3 * DM * DM, DM, 0, biasAttnL + l * 512 + 384,
                        v, LDH, 0, wvb, T, false, false, tid);
    __syncthreads();
    layernorm_add(h, v, ln + ((l * 2 + 0) * 2 + 0) * DM, ln + ((l * 2 + 0) * 2 + 1) * DM, T, tid);
    __syncthreads();
    // FF in two 256-col halves; ff2 accumulates into v
    const float* W1l = W1 + (size_t)l * DM * 512;
    const float* W2l = W2 + (size_t)l * 512 * DM;
    matmul_grp<8, R, 2>(h, LDH, W1l, 512, 128, biasB1L + l * 512,
                        hidden, LDF, 128, wvb, T, true, false, tid);
    __syncthreads();
    matmul_grp<16, R, 1>(hidden, LDF, W2l, DM, 0, biasB2L + l * 128,
                         v, LDH, 0, wvb, T, false, false, tid);
    __syncthreads();
    matmul_grp<8, R, 2>(h, LDH, W1l + 256, 512, 128, biasB1L + l * 512 + 256,
                        hidden, LDF, 128, wvb, T, true, false, tid);
    __syncthreads();
    matmul_grp<16, R, 1>(hidden, LDF, W2l + (size_t)256 * DM, DM, 0, biasB2L + l * 128,
                         v, LDH, 0, wvb, T, false, true, tid);
    __syncthreads();
    layernorm_add(h, v, ln + ((l * 2 + 1) * 2 + 0) * DM, ln + ((l * 2 + 1) * 2 + 1) * DM, T, tid);
    __syncthreads();
  }
}

__global__ __launch_bounds__(NT, 1)
void tsp_kernel(Params p)
{
  const int b = blockIdx.x;
  const int tid = threadIdx.x;
  const int lane = tid & 63;
  const int wv = tid >> 6;

  extern __shared__ float sm[];
  float* hA   = sm + OFF_HA;
  float* hS   = sm + OFF_HS;
  float* bias = sm + OFF_BIAS;
  float* swb  = sm + OFF_WBUF;
  float* wvb  = sm + OFF_WBUF + wv * 1024;
  float* scr  = sm + OFF_SCR;

  __shared__ float xl[NN * 2];
  __shared__ int   maskS[NN];
  __shared__ int   knnS[KS];
  __shared__ int   validS[KA];
  __shared__ float d2S[NN];
  __shared__ float tokA[TA * 2];
  __shared__ float tokS[TS * 2];
  __shared__ int   lastS;
  __shared__ float logpS;

  // ---- init: coords, mask, bias preload ----
  for (int i = tid; i < NN * 2; i += NT) xl[i] = p.x[b * NN * 2 + i];
  for (int i = tid; i < 1024; i += NT) bias[B_ATTN_A + i] = p.a_attn_b[i];
  for (int i = tid; i < 1024; i += NT) bias[B_ATTN_S + i] = p.s_attn_b[i];
  for (int i = tid; i < 1024; i += NT) bias[B_FF1_A + i] = p.a_ff_b1[i];
  for (int i = tid; i < 1024; i += NT) bias[B_FF1_S + i] = p.s_ff_b1[i];
  for (int i = tid; i < 256; i += NT) bias[B_FF2_A + i] = p.a_ff_b2[i];
  for (int i = tid; i < 256; i += NT) bias[B_FF2_S + i] = p.s_ff_b2[i];
  for (int i = tid; i < 256; i += NT) bias[B_K + i] = p.bK[i];
  for (int i = tid; i < 256; i += NT) bias[B_V + i] = p.bV[i];
  const int st = p.start[b];
  for (int i = tid; i < NN; i += NT) maskS[i] = (i != st) ? 1 : 0;
  if (tid == 0) {
    lastS = st; logpS = 0.f;
    p.out[b * NN] = (float)st;
  }
  __syncthreads();
  const float fx = xl[2 * st], fy = xl[2 * st + 1];

  for (int t = 0; t < NN - 1; ++t) {
    const int last = lastS;
    const float lx = xl[2 * last], ly = xl[2 * last + 1];

    // ---- squared distances (no FMA contraction: match np bit-exact) ----
    for (int j = tid; j < NN; j += NT) {
      float dx = __fsub_rn(xl[2 * j], lx);
      float dy = __fsub_rn(xl[2 * j + 1], ly);
      float dd = __fadd_rn(__fmul_rn(dx, dx), __fmul_rn(dy, dy));
      d2S[j] = maskS[j] ? dd : BIGF;
    }
    __syncthreads();

    // ---- stable top-KS (ascending d2, ties -> lowest index), wave 0 ----
    if (wv == 0) {
      float v = (lane < NN) ? d2S[lane] : 2.0f * BIGF;
      const int vi = lane;
      for (int s2 = 0; s2 < KS; ++s2) {
        float mv = v; int mi = vi;
        for (int off = 32; off; off >>= 1) {
          float ov = __shfl_xor(mv, off);
          int oi = __shfl_xor(mi, off);
          if (ov < mv || (ov == mv && oi < mi)) { mv = ov; mi = oi; }
        }
        if (lane == 0) knnS[s2] = mi;
        if (vi == mi) v = 4.0f * BIGF;
      }
    }
    __syncthreads();

    // ---- valid flags + tokens ----
    if (tid < KA) validS[tid] = maskS[knnS[tid]];
    if (tid < KS) { int j = knnS[tid]; tokS[2 * tid] = xl[2 * j]; tokS[2 * tid + 1] = xl[2 * j + 1]; }
    if (tid < KA) { int j = knnS[tid]; tokA[2 * tid] = xl[2 * j]; tokA[2 * tid + 1] = xl[2 * j + 1]; }
    if (tid == NT - 1) { tokA[2 * KA] = lx; tokA[2 * KA + 1] = ly; }
    if (tid == NT - 2) { tokS[2 * KS] = lx; tokS[2 * KS + 1] = ly; }
    if (tid == NT - 3) { tokS[2 * KS + 2] = fx; tokS[2 * KS + 3] = fy; }
    __syncthreads();

    // ---- encoders (outputs persist in hA/hS, stride LDH) ----
    encode_block<TA, 1>(hA, scr, swb, wvb, tokA, p.a_emb_W, p.a_emb_b,
                        p.a_attn_W, bias + B_ATTN_A, p.a_ff_W1, bias + B_FF1_A,
                        p.a_ff_W2, bias + B_FF2_A, p.a_ln, tid);
    encode_block<TS, 3>(hS, scr, swb, wvb, tokS, p.s_emb_W, p.s_emb_b,
                        p.s_attn_W, bias + B_ATTN_S, p.s_ff_W1, bias + B_FF1_S,
                        p.s_ff_W2, bias + B_FF2_S, p.s_ln, tid);

    // ---- decoder scratch in scr ----
    float* embq = scr;             // 384
    float* embo = scr + 384;       // 15 x 260
    float* Kd   = scr + 4284;      // 15 x 260
    float* Vd   = scr + 8184;      // 15 x 260
    float* hdec = scr + 12084;     // 128
    float* qd   = scr + 12212;     // 128
    float* scd  = scr + 12340;     // 120
    float* od   = scr + 12460;     // 128
    float* tmp  = scr + 12588;     // 128
    float* red  = scr + 12716;     // 512

    if (tid < 384) {
      embq[tid] = (tid < 128) ? hA[KA * LDH + tid]
                : (tid < 256) ? hS[KS * LDH + (tid - 128)]
                              : hS[(KS + 1) * LDH + (tid - 256)];
    }
    for (int idx = tid; idx < KA * 256; idx += NT) {
      int r = idx >> 8, c = idx & 255;
      embo[r * LDF + c] = (c < 128) ? hA[r * LDH + c] : hS[r * LDH + (c - 128)];
    }
    __syncthreads();

    matmul_grp<16, 1, 2>(embo, LDF, p.WK, 256, 128, bias + B_K,
                         Kd, LDF, 128, wvb, KA, false, false, tid);
    matmul_grp<16, 1, 2>(embo, LDF, p.WV, 256, 128, bias + B_V,
                         Vd, LDF, 128, wvb, KA, false, false, tid);
    matvec128(embq, p.Wq_mlp, p.bq_mlp, hdec, 384, red, tid);  // internal syncs cover K/V

    // ---- decoder layer 0 (cross-attention) ----
    matvec128(hdec, p.d_Wq, p.d_bq, qd, DM, red, tid);
    if (tid < NHD * KA) {
      int hd = tid / KA, kk2 = tid - hd * KA;
      const float* qh = qd + hd * HDM;
      const float* kh = Kd + kk2 * LDF + hd * HDM;
      float acc = 0.f;
#pragma unroll
      for (int d = 0; d < HDM; ++d) acc += qh[d] * kh[d];
      acc = acc / 4.0f;
      scd[tid] = validS[kk2] ? acc : -BIGF;
    }
    __syncthreads();
    if (tid < NHD) {
      float mx = -INFINITY;
#pragma unroll
      for (int kk2 = 0; kk2 < KA; ++kk2) mx = fmaxf(mx, scd[tid * KA + kk2]);
      float e[KA]; float sum = 0.f;
#pragma unroll
      for (int kk2 = 0; kk2 < KA; ++kk2) { e[kk2] = expf(scd[tid * KA + kk2] - mx); sum += e[kk2]; }
      float inv = 1.0f / sum;
#pragma unroll
      for (int kk2 = 0; kk2 < KA; ++kk2) scd[tid * KA + kk2] = e[kk2] * inv;
    }
    __syncthreads();
    if (tid < DM) {
      int hd = tid >> 4;
      float acc = 0.f;
#pragma unroll
      for (int kk2 = 0; kk2 < KA; ++kk2) acc = fmaf(scd[hd * KA + kk2], Vd[kk2 * LDF + tid], acc);
      od[tid] = acc;
    }
    __syncthreads();
    matvec128(od, p.d_Wo, p.d_bo, tmp, DM, red, tid);
    if (tid < DM) hdec[tid] += tmp[tid];
    __syncthreads();

    // ---- final pointer logits ----
    matvec128(hdec, p.d_Wq + DM * DM, p.d_bq + DM, qd, DM, red, tid);
    if (wv == 0) {
      float lg = -BIGF;
      if (lane < KA) {
        const float* kf = Kd + lane * LDF + 128;  // K[:, :, 1]
        float acc = 0.f;
#pragma unroll 8
        for (int d = 0; d < DM; ++d) acc = fmaf(qd[d], kf[d], acc);
        acc = acc / 11.313708498984761f;  // sqrt(128)
        lg = validS[lane] ? 10.0f * tanhf(acc) : -BIGF;
      }
      float mv = lg; int mi = (lane < KA) ? lane : 1000;
      for (int off = 32; off; off >>= 1) {
        float ov = __shfl_xor(mv, off);
        int oi = __shfl_xor(mi, off);
        if (ov > mv || (ov == mv && oi < mi)) { mv = ov; mi = oi; }
      }
      float e = (lane < KA) ? expf(lg - mv) : 0.f;
      float sum = e;
      for (int off = 32; off; off >>= 1) sum += __shfl_xor(sum, off);
      if (lane == 0) {
        int nxt = knnS[mi];
        logpS += -logf(sum);
        maskS[nxt] = 0;
        lastS = nxt;
        p.out[b * NN + t + 1] = (float)nxt;
      }
    }
    __syncthreads();
  }

  if (tid == 0) p.out[NB * NN + b] = logpS;
}

} // namespace

extern "C" void kernel_launch(void* const* d_in, const int* in_sizes, int n_in,
                              void* d_out, int out_size, void* d_ws, size_t ws_size,
                              hipStream_t stream)
{
  (void)in_sizes; (void)n_in; (void)out_size; (void)d_ws; (void)ws_size;
  Params p;
  p.x        = (const float*)d_in[0];
  p.start    = (const int*)d_in[1];
  // d_in[2]=action_k (15), d_in[3]=state_k (35): fixed by problem, hardcoded.
  p.a_emb_W  = (const float*)d_in[4];
  p.a_emb_b  = (const float*)d_in[5];
  p.a_attn_W = (const float*)d_in[6];
  p.a_attn_b = (const float*)d_in[7];
  p.a_ff_W1  = (const float*)d_in[8];
  p.a_ff_b1  = (const float*)d_in[9];
  p.a_ff_W2  = (const float*)d_in[10];
  p.a_ff_b2  = (const float*)d_in[11];
  p.a_ln     = (const float*)d_in[12];
  p.s_emb_W  = (const float*)d_in[13];
  p.s_emb_b  = (const float*)d_in[14];
  p.s_attn_W = (const float*)d_in[15];
  p.s_attn_b = (const float*)d_in[16];
  p.s_ff_W1  = (const float*)d_in[17];
  p.s_ff_b1  = (const float*)d_in[18];
  p.s_ff_W2  = (const float*)d_in[19];
  p.s_ff_b2  = (const float*)d_in[20];
  p.s_ln     = (const float*)d_in[21];
  p.WK       = (const float*)d_in[22];
  p.bK       = (const float*)d_in[23];
  p.WV       = (const float*)d_in[24];
  p.bV       = (const float*)d_in[25];
  p.Wq_mlp   = (const float*)d_in[26];
  p.bq_mlp   = (const float*)d_in[27];
  p.d_Wq     = (const float*)d_in[28];
  p.d_bq     = (const float*)d_in[29];
  p.d_Wo     = (const float*)d_in[30];
  p.d_bo     = (const float*)d_in[31];
  p.out      = (float*)d_out;

  (void)hipFuncSetAttribute((const void*)tsp_kernel,
                            hipFuncAttributeMaxDynamicSharedMemorySize, SMEM_BYTES);
  tsp_kernel<<<NB, NT, SMEM_BYTES, stream>>>(p);
}

// Round 13
// 50466.428 us; speedup vs baseline: 4.1833x; 4.1833x over previous
//
#include <hip/hip_runtime.h>

namespace {

constexpr int NB  = 64;    // batch
constexpr int NN  = 50;    // nodes
constexpr int DM  = 128;   // model dim
constexpr int FFDIM = 512;
constexpr int NHD = 8;     // heads
constexpr int HDM = 16;    // head dim
constexpr int KA  = 15;    // action_k
constexpr int KS  = 35;    // state_k
constexpr int TA  = 16;    // KA+1 tokens (encoder A)
constexpr int TS  = 37;    // KS+2 tokens (encoder S)
constexpr int NT  = 512;   // threads per block
constexpr float BIGF = 1000000000.0f;

// dynamic LDS (floats) -- R4 sizing (no weight buffers)
constexpr int OFF_HA  = 0;       // 16*128 = 2048
constexpr int OFF_HS  = 2048;    // 37*128 = 4736
constexpr int OFF_SCR = 6784;
constexpr int SCR_FLOATS = 25160;   // max(attn: 3*37*128+8*37*37, ff: 37*512+37*128)
constexpr int SMEM_FLOATS = OFF_SCR + SCR_FLOATS;   // 31944
constexpr int SMEM_BYTES  = SMEM_FLOATS * 4;        // 127776 B

struct Params {
  const float* x; const int* start;
  const float* a_emb_W; const float* a_emb_b;
  const float* a_attn_W; const float* a_attn_b;
  const float* a_ff_W1; const float* a_ff_b1;
  const float* a_ff_W2; const float* a_ff_b2;
  const float* a_ln;
  const float* s_emb_W; const float* s_emb_b;
  const float* s_attn_W; const float* s_attn_b;
  const float* s_ff_W1; const float* s_ff_b1;
  const float* s_ff_W2; const float* s_ff_b2;
  const float* s_ln;
  const float* WK; const float* bK;
  const float* WV; const float* bV;
  const float* Wq_mlp; const float* bq_mlp;
  const float* d_Wq; const float* d_bq;
  const float* d_Wo; const float* d_bo;
  float* out;   // f32: tours (64x50) ++ logp (64)
};

// Register-row-tiled matmul (R4's proven inner loop; compile-time C for non-pow2 blocks):
// out[T x C] = in[T x K] @ W + bias (+relu). Thread owns 4 cols x R rows; weight float4
// loaded once per row-group; redundancy = ceil(T/R) groups. C = fused CB-col blocks
// (block m: W+m*wBlk, bias+m*CB, out+m*oBlk). No barriers inside. Threads with
// rb>=T return early. ACCUM: init acc from out (K-split accumulation).
template<int C, int CB, int K, int R, bool ACCUM>
__device__ inline void matmul_deep(const float* __restrict__ in, int lda,
                                   const float* __restrict__ W, int ldw, int wBlk,
                                   const float* __restrict__ bias,
                                   float* __restrict__ out, int ldo, int oBlk,
                                   int T, bool relu, int tid)
{
  constexpr int NCOL = C >> 2;   // float4 columns
  constexpr int C4B  = CB >> 2;
  const int cw = tid % NCOL;
  const int g  = tid / NCOL;
  const int rb = g * R;
  if (rb >= T) return;
  const int m  = cw / C4B;
  const int ci = (cw % C4B) << 2;
  const float* __restrict__ wp = W + (size_t)m * wBlk + ci;
  float* __restrict__ op = out + (size_t)m * oBlk + ci;
  int ro[R];
#pragma unroll
  for (int i = 0; i < R; ++i) ro[i] = min(rb + i, T - 1) * lda;
  float4 acc[R];
  if (ACCUM) {
#pragma unroll
    for (int i = 0; i < R; ++i) acc[i] = *(const float4*)(op + min(rb + i, T - 1) * ldo);
  } else {
    const float4 bv = *(const float4*)(bias + m * CB + ci);
#pragma unroll
    for (int i = 0; i < R; ++i) acc[i] = bv;
  }
#define FMA16_(aa, i, w0, w1, w2, w3) \
  acc[i].x = fmaf((aa).x,(w0).x,acc[i].x); acc[i].y = fmaf((aa).x,(w0).y,acc[i].y); \
  acc[i].z = fmaf((aa).x,(w0).z,acc[i].z); acc[i].w = fmaf((aa).x,(w0).w,acc[i].w); \
  acc[i].x = fmaf((aa).y,(w1).x,acc[i].x); acc[i].y = fmaf((aa).y,(w1).y,acc[i].y); \
  acc[i].z = fmaf((aa).y,(w1).z,acc[i].z); acc[i].w = fmaf((aa).y,(w1).w,acc[i].w); \
  acc[i].x = fmaf((aa).z,(w2).x,acc[i].x); acc[i].y = fmaf((aa).z,(w2).y,acc[i].y); \
  acc[i].z = fmaf((aa).z,(w2).z,acc[i].z); acc[i].w = fmaf((aa).z,(w2).w,acc[i].w); \
  acc[i].x = fmaf((aa).w,(w3).x,acc[i].x); acc[i].y = fmaf((aa).w,(w3).y,acc[i].y); \
  acc[i].z = fmaf((aa).w,(w3).z,acc[i].z); acc[i].w = fmaf((aa).w,(w3).w,acc[i].w);
#pragma unroll 2
  for (int kk = 0; kk < K; kk += 4) {
    float4 w0 = *(const float4*)(wp + (size_t)(kk    ) * ldw);
    float4 w1 = *(const float4*)(wp + (size_t)(kk + 1) * ldw);
    float4 w2 = *(const float4*)(wp + (size_t)(kk + 2) * ldw);
    float4 w3 = *(const float4*)(wp + (size_t)(kk + 3) * ldw);
#pragma unroll
    for (int i = 0; i < R; ++i) {
      float4 a = *(const float4*)(in + ro[i] + kk);
      FMA16_(a, i, w0, w1, w2, w3);
    }
  }
#pragma unroll
  for (int i = 0; i < R; ++i) {
    if (rb + i < T) {
      float4 r2 = acc[i];
      if (relu) {
        r2.x = fmaxf(r2.x, 0.f); r2.y = fmaxf(r2.y, 0.f);
        r2.z = fmaxf(r2.z, 0.f); r2.w = fmaxf(r2.w, 0.f);
      }
      *(float4*)(op + (rb + i) * ldo) = r2;
    }
  }
#undef FMA16_
}

// out[0..128) = bias + in(1xK) @ W(Kx128). K sliced 4-way, LDS-reduced. 2 barriers.
__device__ inline void matvec128(const float* __restrict__ in, const float* __restrict__ W,
                                 const float* __restrict__ bias, float* __restrict__ out,
                                 int K, float* __restrict__ red, int tid)
{
  const int c = tid & 127;
  const int s = tid >> 7;      // 0..3
  const int ks = K >> 2;
  const int k0 = s * ks;
  float acc = 0.f;
#pragma unroll 16
  for (int k = k0; k < k0 + ks; ++k) acc = fmaf(in[k], W[(size_t)k * 128 + c], acc);
  red[tid] = acc;
  __syncthreads();
  if (tid < 128) out[c] = bias[c] + ((red[c] + red[128 + c]) + (red[256 + c] + red[384 + c]));
  __syncthreads();
}

// h[r] = LN(h[r] + a1[r]). One wave per row.
__device__ inline void layernorm_add(float* __restrict__ h, const float* __restrict__ a1,
                                     const float* __restrict__ g, const float* __restrict__ bta,
                                     int T, int tid)
{
  const int lane = tid & 63;
  const int wvl = tid >> 6;
  for (int r = wvl; r < T; r += NT / 64) {
    float v0 = h[r * DM + lane]      + a1[r * DM + lane];
    float v1 = h[r * DM + lane + 64] + a1[r * DM + lane + 64];
    float sum = v0 + v1;
    for (int off = 32; off; off >>= 1) sum += __shfl_xor(sum, off);
    float mu = sum * (1.0f / 128.0f);
    float d0 = v0 - mu, d1 = v1 - mu;
    float sq = d0 * d0 + d1 * d1;
    for (int off = 32; off; off >>= 1) sq += __shfl_xor(sq, off);
    float rs = 1.0f / sqrtf(sq * (1.0f / 128.0f) + 1e-5f);
    h[r * DM + lane]      = g[lane]      * d0 * rs + bta[lane];
    h[r * DM + lane + 64] = g[lane + 64] * d1 * rs + bta[lane + 64];
  }
}

// 2-layer post-LN transformer encoder, all NT threads. h persists (T x 128).
// RQKV: fused QKV (C=384, ceil(T/RQKV) groups of 96 thr); RWO: Wo (C=128);
// RFF1: FF1 (C=512); RFF2: FF2 halves (C=128, K=256 each).
template<int T, int RQKV, int RWO, int RFF1, int RFF2>
__device__ void encode_block(float* __restrict__ h, float* __restrict__ scr,
                             const float* __restrict__ tok,
                             const float* __restrict__ embW, const float* __restrict__ embB,
                             const float* __restrict__ attnW, const float* __restrict__ attnB,
                             const float* __restrict__ W1, const float* __restrict__ b1,
                             const float* __restrict__ W2, const float* __restrict__ b2,
                             const float* __restrict__ ln, int tid)
{
  const int lane = tid & 63;
  const int wvl = tid >> 6;
  constexpr int TT = T * T;
  float* q = scr;                 // T*128
  float* k = scr + T * DM;        // T*128
  float* v = scr + 2 * T * DM;    // T*128
  float* s = scr + 3 * T * DM;    // scores 8*T*T
  // embedding: h = tok(Tx2) @ embW(2x128) + embB
  for (int idx = tid; idx < T * DM; idx += NT) {
    int r = idx >> 7, c = idx & 127;
    h[idx] = tok[2 * r] * embW[c] + tok[2 * r + 1] * embW[DM + c] + embB[c];
  }
  __syncthreads();
  for (int l = 0; l < 2; ++l) {
    const float* Wl = attnW + (size_t)(l * 4) * DM * DM;   // Wq,Wk,Wv,Wo contiguous
    const float* bl = attnB + (l * 4) * DM;                // bq,bk,bv,bo contiguous
    // fused QKV: C=384 (3 blocks of 128 cols), K=128
    matmul_deep<384, 128, 128, RQKV, false>(h, DM, Wl, DM, DM * DM, bl,
                                            q, DM, T * DM, T, false, tid);
    __syncthreads();
    // scores s[hd][i][j] = (q_i,hd . k_j,hd) / 4
    for (int idx = tid; idx < NHD * TT; idx += NT) {
      int hd = idx / TT; int rem = idx - hd * TT; int i = rem / T; int j = rem - i * T;
      const float4* q4 = (const float4*)(q + i * DM + hd * HDM);
      const float4* k4 = (const float4*)(k + j * DM + hd * HDM);
      float acc = 0.f;
#pragma unroll
      for (int d = 0; d < 4; ++d) {
        float4 qa = q4[d], ka = k4[d];
        acc += qa.x * ka.x + qa.y * ka.y + qa.z * ka.z + qa.w * ka.w;
      }
      s[idx] = acc * 0.25f;
    }
    __syncthreads();
    // row softmax
    for (int r = wvl; r < NHD * T; r += NT / 64) {
      float val = (lane < T) ? s[r * T + lane] : -INFINITY;
      float mx = val;
      for (int off = 32; off; off >>= 1) mx = fmaxf(mx, __shfl_xor(mx, off));
      float e = (lane < T) ? expf(val - mx) : 0.f;
      float sum = e;
      for (int off = 32; off; off >>= 1) sum += __shfl_xor(sum, off);
      if (lane < T) s[r * T + lane] = e / sum;
    }
    __syncthreads();
    // attn out -> q (q dead after scores)
    for (int idx = tid; idx < T * DM; idx += NT) {
      int i = idx >> 7, c = idx & 127; int hd = c >> 4;
      const float* ar = s + (hd * T + i) * T;
      float acc = 0.f;
#pragma unroll 4
      for (int j = 0; j < T; ++j) acc = fmaf(ar[j], v[j * DM + c], acc);
      q[idx] = acc;
    }
    __syncthreads();
    // Wo: q -> v (v dead), then h = LN(h + v)
    matmul_deep<128, 128, 128, RWO, false>(q, DM, Wl + (size_t)3 * DM * DM, DM, 0, bl + 3 * DM,
                                           v, DM, 0, T, false, tid);
    __syncthreads();
    layernorm_add(h, v, ln + ((l * 2 + 0) * 2 + 0) * DM, ln + ((l * 2 + 0) * 2 + 1) * DM, T, tid);
    __syncthreads();
    // FF1: hidden = relu(h@W1+b1); hidden at scr[0..T*512) (q/k/v/s dead)
    const float* W1l = W1 + (size_t)l * DM * FFDIM;
    const float* W2l = W2 + (size_t)l * FFDIM * DM;
    float* hidden = scr;
    float* ff2o   = scr + T * FFDIM;   // T*128
    matmul_deep<512, 512, 128, RFF1, false>(h, DM, W1l, FFDIM, 0, b1 + l * FFDIM,
                                            hidden, FFDIM, 0, T, true, tid);
    __syncthreads();
    // FF2: K=512 as two accumulating K=256 halves (no barrier between: same input, disjoint k)
    matmul_deep<128, 128, 256, RFF2, false>(hidden, FFDIM, W2l, DM, 0, b2 + l * DM,
                                            ff2o, DM, 0, T, false, tid);
    __syncthreads();
    matmul_deep<128, 128, 256, RFF2, true>(hidden + 256, FFDIM, W2l + (size_t)256 * DM, DM, 0,
                                           b2 + l * DM, ff2o, DM, 0, T, false, tid);
    __syncthreads();
    layernorm_add(h, ff2o, ln + ((l * 2 + 1) * 2 + 0) * DM, ln + ((l * 2 + 1) * 2 + 1) * DM, T, tid);
    __syncthreads();
  }
}

__global__ __launch_bounds__(NT, 1)
void tsp_kernel(Params p)
{
  const int b = blockIdx.x;
  const int tid = threadIdx.x;
  const int lane = tid & 63;
  const int wv = tid >> 6;

  extern __shared__ float sm[];
  float* hA  = sm + OFF_HA;
  float* hS  = sm + OFF_HS;
  float* scr = sm + OFF_SCR;

  __shared__ float xl[NN * 2];
  __shared__ int   maskS[NN];
  __shared__ int   knnS[KS];
  __shared__ int   validS[KA];
  __shared__ float d2S[NN];
  __shared__ float tokA[TA * 2];
  __shared__ float tokS[TS * 2];
  __shared__ int   lastS;
  __shared__ float logpS;

  // ---- init ----
  for (int i = tid; i < NN * 2; i += NT) xl[i] = p.x[b * NN * 2 + i];
  const int st = p.start[b];
  for (int i = tid; i < NN; i += NT) maskS[i] = (i != st) ? 1 : 0;
  if (tid == 0) {
    lastS = st; logpS = 0.f;
    p.out[b * NN] = (float)st;
  }
  __syncthreads();
  const float fx = xl[2 * st], fy = xl[2 * st + 1];

  for (int t = 0; t < NN - 1; ++t) {
    const int last = lastS;
    const float lx = xl[2 * last], ly = xl[2 * last + 1];

    // ---- squared distances, masked -> BIG (no FMA contraction: match np bit-exact) ----
    for (int j = tid; j < NN; j += NT) {
      float dx = __fsub_rn(xl[2 * j], lx);
      float dy = __fsub_rn(xl[2 * j + 1], ly);
      float dd = __fadd_rn(__fmul_rn(dx, dx), __fmul_rn(dy, dy));
      d2S[j] = maskS[j] ? dd : BIGF;
    }
    __syncthreads();

    // ---- stable top-KS (ascending d2, ties -> lowest index), wave 0 ----
    if (wv == 0) {
      float v = (lane < NN) ? d2S[lane] : 2.0f * BIGF;
      const int vi = lane;
      for (int s2 = 0; s2 < KS; ++s2) {
        float mv = v; int mi = vi;
        for (int off = 32; off; off >>= 1) {
          float ov = __shfl_xor(mv, off);
          int oi = __shfl_xor(mi, off);
          if (ov < mv || (ov == mv && oi < mi)) { mv = ov; mi = oi; }
        }
        if (lane == 0) knnS[s2] = mi;
        if (vi == mi) v = 4.0f * BIGF;  // remove winner
      }
    }
    __syncthreads();

    // ---- valid flags + tokens ----
    if (tid < KA) validS[tid] = maskS[knnS[tid]];
    if (tid < KS) { int j = knnS[tid]; tokS[2 * tid] = xl[2 * j]; tokS[2 * tid + 1] = xl[2 * j + 1]; }
    if (tid < KA) { int j = knnS[tid]; tokA[2 * tid] = xl[2 * j]; tokA[2 * tid + 1] = xl[2 * j + 1]; }
    if (tid == NT - 1) { tokA[2 * KA] = lx; tokA[2 * KA + 1] = ly; }
    if (tid == NT - 2) { tokS[2 * KS] = lx; tokS[2 * KS + 1] = ly; }
    if (tid == NT - 3) { tokS[2 * KS + 2] = fx; tokS[2 * KS + 3] = fy; }
    __syncthreads();

    // ---- encoder A (16 tok) then encoder S (37 tok); outputs persist in hA/hS ----
    encode_block<TA, 8, 8, 8, 8>(hA, scr, tokA, p.a_emb_W, p.a_emb_b, p.a_attn_W, p.a_attn_b,
                                 p.a_ff_W1, p.a_ff_b1, p.a_ff_W2, p.a_ff_b2, p.a_ln, tid);
    encode_block<TS, 8, 10, 10, 10>(hS, scr, tokS, p.s_emb_W, p.s_emb_b, p.s_attn_W, p.s_attn_b,
                                    p.s_ff_W1, p.s_ff_b1, p.s_ff_W2, p.s_ff_b2, p.s_ln, tid);

    // ---- decoder scratch in scr ----
    float* embq = scr;            // 384
    float* embo = scr + 384;      // 15 x 256
    float* Kd   = scr + 4224;     // 15 x 256
    float* Vd   = scr + 8064;     // 15 x 256
    float* hdec = scr + 11904;    // 128
    float* qd   = scr + 12032;    // 128
    float* scd  = scr + 12160;    // 120
    float* od   = scr + 12288;    // 128
    float* tmp  = scr + 12416;    // 128
    float* red  = scr + 12544;    // 512

    if (tid < 384) {
      embq[tid] = (tid < 128) ? hA[KA * DM + tid]
                : (tid < 256) ? hS[KS * DM + (tid - 128)]
                              : hS[(KS + 1) * DM + (tid - 256)];
    }
    for (int idx = tid; idx < KA * 256; idx += NT) {
      int r = idx >> 8, c = idx & 255;
      embo[idx] = (c < 128) ? hA[r * DM + c] : hS[r * DM + (c - 128)];
    }
    __syncthreads();

    // K/V: 15x256 = embo(15x256) @ WK/WV(256x256); 2 row-groups each (R=8)
    matmul_deep<256, 256, 256, 8, false>(embo, 256, p.WK, 256, 0, p.bK,
                                         Kd, 256, 0, KA, false, tid);
    matmul_deep<256, 256, 256, 8, false>(embo, 256, p.WV, 256, 0, p.bV,
                                         Vd, 256, 0, KA, false, tid);
    matvec128(embq, p.Wq_mlp, p.bq_mlp, hdec, 384, red, tid);  // internal syncs order K/V too

    // ---- decoder layer 0 (cross-attention) ----
    matvec128(hdec, p.d_Wq, p.d_bq, qd, DM, red, tid);
    if (tid < NHD * KA) {   // 120 threads
      int hd = tid / KA, kk2 = tid - hd * KA;
      const float* qh = qd + hd * HDM;
      const float* kh = Kd + kk2 * 256 + hd * HDM;
      float acc = 0.f;
#pragma unroll
      for (int d = 0; d < HDM; ++d) acc += qh[d] * kh[d];
      acc = acc / 4.0f;
      scd[tid] = validS[kk2] ? acc : -BIGF;
    }
    __syncthreads();
    if (tid < NHD) {
      float mx = -INFINITY;
#pragma unroll
      for (int kk2 = 0; kk2 < KA; ++kk2) mx = fmaxf(mx, scd[tid * KA + kk2]);
      float e[KA]; float sum = 0.f;
#pragma unroll
      for (int kk2 = 0; kk2 < KA; ++kk2) { e[kk2] = expf(scd[tid * KA + kk2] - mx); sum += e[kk2]; }
      float inv = 1.0f / sum;
#pragma unroll
      for (int kk2 = 0; kk2 < KA; ++kk2) scd[tid * KA + kk2] = e[kk2] * inv;
    }
    __syncthreads();
    if (tid < DM) {
      int hd = tid >> 4;
      float acc = 0.f;
#pragma unroll
      for (int kk2 = 0; kk2 < KA; ++kk2) acc = fmaf(scd[hd * KA + kk2], Vd[kk2 * 256 + tid], acc);
      od[tid] = acc;
    }
    __syncthreads();
    matvec128(od, p.d_Wo, p.d_bo, tmp, DM, red, tid);
    if (tid < DM) hdec[tid] += tmp[tid];
    __syncthreads();

    // ---- final pointer logits ----
    matvec128(hdec, p.d_Wq + DM * DM, p.d_bq + DM, qd, DM, red, tid);
    if (wv == 0) {
      float lg = -BIGF;
      if (lane < KA) {
        const float* kf = Kd + lane * 256 + 128;  // K[:, :, 1]
        float acc = 0.f;
#pragma unroll 8
        for (int d = 0; d < DM; ++d) acc = fmaf(qd[d], kf[d], acc);
        acc = acc / 11.313708498984761f;  // sqrt(128)
        lg = validS[lane] ? 10.0f * tanhf(acc) : -BIGF;
      }
      // argmax, ties -> lowest index (== argmax of softmax probs)
      float mv = lg; int mi = (lane < KA) ? lane : 1000;
      for (int off = 32; off; off >>= 1) {
        float ov = __shfl_xor(mv, off);
        int oi = __shfl_xor(mi, off);
        if (ov > mv || (ov == mv && oi < mi)) { mv = ov; mi = oi; }
      }
      float e = (lane < KA) ? expf(lg - mv) : 0.f;
      float sum = e;
      for (int off = 32; off; off >>= 1) sum += __shfl_xor(sum, off);
      if (lane == 0) {
        int nxt = knnS[mi];
        logpS += -logf(sum);  // lg[mi] - mv == 0
        maskS[nxt] = 0;
        lastS = nxt;
        p.out[b * NN + t + 1] = (float)nxt;
      }
    }
    __syncthreads();
  }

  if (tid == 0) p.out[NB * NN + b] = logpS;
}

} // namespace

extern "C" void kernel_launch(void* const* d_in, const int* in_sizes, int n_in,
                              void* d_out, int out_size, void* d_ws, size_t ws_size,
                              hipStream_t stream)
{
  (void)in_sizes; (void)n_in; (void)out_size; (void)d_ws; (void)ws_size;
  Params p;
  p.x        = (const float*)d_in[0];
  p.start    = (const int*)d_in[1];
  // d_in[2]=action_k (15), d_in[3]=state_k (35): fixed by problem, hardcoded.
  p.a_emb_W  = (const float*)d_in[4];
  p.a_emb_b  = (const float*)d_in[5];
  p.a_attn_W = (const float*)d_in[6];
  p.a_attn_b = (const float*)d_in[7];
  p.a_ff_W1  = (const float*)d_in[8];
  p.a_ff_b1  = (const float*)d_in[9];
  p.a_ff_W2  = (const float*)d_in[10];
  p.a_ff_b2  = (const float*)d_in[11];
  p.a_ln     = (const float*)d_in[12];
  p.s_emb_W  = (const float*)d_in[13];
  p.s_emb_b  = (const float*)d_in[14];
  p.s_attn_W = (const float*)d_in[15];
  p.s_attn_b = (const float*)d_in[16];
  p.s_ff_W1  = (const float*)d_in[17];
  p.s_ff_b1  = (const float*)d_in[18];
  p.s_ff_W2  = (const float*)d_in[19];
  p.s_ff_b2  = (const float*)d_in[20];
  p.s_ln     = (const float*)d_in[21];
  p.WK       = (const float*)d_in[22];
  p.bK       = (const float*)d_in[23];
  p.WV       = (const float*)d_in[24];
  p.bV       = (const float*)d_in[25];
  p.Wq_mlp   = (const float*)d_in[26];
  p.bq_mlp   = (const float*)d_in[27];
  p.d_Wq     = (const float*)d_in[28];
  p.d_bq     = (const float*)d_in[29];
  p.d_Wo     = (const float*)d_in[30];
  p.d_bo     = (const float*)d_in[31];
  p.out      = (float*)d_out;

  (void)hipFuncSetAttribute((const void*)tsp_kernel,
                            hipFuncAttributeMaxDynamicSharedMemorySize, SMEM_BYTES);
  tsp_kernel<<<NB, NT, SMEM_BYTES, stream>>>(p);
}